// Round 7
// baseline (638.448 us; speedup 1.0000x reference)
//
#include <hip/hip_runtime.h>

// Problem dims
constexpr int N_TOK = 2048;   // T*B
constexpr int C_    = 256;    // in features (== R == OUT)
constexpr int NE    = 64;     // experts
constexpr int D_    = 65536;  // R*OUT centroid dim
constexpr float DECAYF = 0.999f;
constexpr float OMD    = 0.001f;
constexpr float ALPHA  = OMD / 2048.0f;   // (1-decay)/N
constexpr float RTHRESH = 1e-5f;
constexpr int CHMAX = 8448;
constexpr int SA_GRIDX = 512;

// ---------- workspace layout (float offsets) ----------
constexpr size_t OFF_S     = 0;        // 65536  S = X^T X (full)
constexpr size_t OFF_XSUM  = 65536;    // 256
constexpr size_t OFF_G     = 65792;    // 65536  G = W^T W (full)
constexpr size_t OFF_M     = 131328;   // 16384  M = cen @ W
constexpr size_t OFF_WB    = 147712;   // 256    Wb = b^T W
constexpr size_t OFF_BB    = 147968;   // 16     bb[0] = ||b||^2
constexpr size_t OFF_SUMR  = 147984;   // 64     sum_n resp
constexpr size_t OFF_A     = 148048;   // 16384  A = resp^T X
constexpr size_t OFF_CC0   = 164432;   // 4096   cen cen^T
constexpr size_t OFF_RR    = 168528;   // 4096   resp^T resp
constexpr size_t OFF_CNT   = 172624;   // 64     per-expert token counts (uint)
constexpr size_t OFF_CN2   = 172688;   // 64
constexpr size_t OFF_CB    = 172752;   // 64
constexpr size_t OFF_TSLOT = 172816;   // 2048   per-token writer count (int)
constexpr size_t ZFLOATS   = 174864;
// overwritten-before-read zone:
constexpr size_t OFF_RESP  = 174864;   // 131072
constexpr size_t OFF_AG    = 174864;   // 16384 (overlay after resp dead)
constexpr size_t OFF_MA    = 191248;   // 4096
constexpr size_t OFF_AGA   = 195344;   // 4096
constexpr size_t OFF_AWB   = 199440;   // 64
constexpr size_t OFF_CHE   = 199504;   // 8448
constexpr size_t OFF_CHB   = 207952;   // 8448
constexpr size_t OFF_NCH   = 216400;   // 16
constexpr size_t OFF_Y     = 305936;   // 524288 y = X @ pw^T
constexpr size_t OFF_CNEW  = 830224;   // 4194304 ; ALSO reused (before k_cnew):
                                       //   k_G partials (4*64*16384 = 4194304, exact fit)
                                       //   then k_M partials (128*16384 = 2.10M)
constexpr size_t OFF_TIDX  = 5024528;  // 131072 (int)
constexpr size_t OFF_TOKR  = 5155600;  // 131072
// total 5286672 floats = 21,146,688 bytes

// ------- centroid stats: cn2[e], cb[e] -------
__global__ __launch_bounds__(256) void k_cstats(const float* __restrict__ cen,
    const float* __restrict__ bmap, float* __restrict__ cn2, float* __restrict__ cb) {
  int e = blockIdx.x >> 2;
  int d0 = (blockIdx.x & 3) * 16384;
  const float* ce = cen + (size_t)e * D_ + d0;
  const float* bm = bmap + d0;
  float s2 = 0.f, sb = 0.f;
  for (int d = threadIdx.x; d < 16384; d += 256) {
    float v = ce[d];
    s2 = fmaf(v, v, s2);
    sb = fmaf(v, bm[d], sb);
  }
  __shared__ float r0[256], r1[256];
  r0[threadIdx.x] = s2; r1[threadIdx.x] = sb;
  __syncthreads();
  for (int s = 128; s > 0; s >>= 1) {
    if (threadIdx.x < s) { r0[threadIdx.x] += r0[threadIdx.x + s];
                           r1[threadIdx.x] += r1[threadIdx.x + s]; }
    __syncthreads();
  }
  if (threadIdx.x == 0) { atomicAdd(&cn2[e], r0[0]); atomicAdd(&cb[e], r1[0]); }
}

// ---------------- bb[0] = ||b||^2 ----------------
__global__ __launch_bounds__(256) void k_bb(const float* __restrict__ bmap, float* __restrict__ bb) {
  int base = blockIdx.x * 16384 + threadIdx.x;
  float s = 0.f;
  for (int q = 0; q < 64; q++) { float v = bmap[base + q * 256]; s = fmaf(v, v, s); }
  __shared__ float red[256];
  red[threadIdx.x] = s;
  __syncthreads();
  for (int k = 128; k > 0; k >>= 1) {
    if (threadIdx.x < k) red[threadIdx.x] += red[threadIdx.x + k];
    __syncthreads();
  }
  if (threadIdx.x == 0) atomicAdd(&bb[0], red[0]);
}

// ======== generic 64x64 gram-style tile (S / A2 / RR2) ========
template<int KCHUNK>
__device__ __forceinline__ void gemm_tt_tile(
    const float* __restrict__ Aop, int lda, int ca,
    const float* __restrict__ Bop, int ldb, int cb,
    int d0, float* __restrict__ Out, int ldo, int ro, int co) {
  __shared__ float Wa[32][68], Wb[32][68];
  int t = threadIdx.x;
  int tx = t & 15, ty = t >> 4;
  int lr = t >> 3, lc = (t & 7) * 8;
  float acc[4][4] = {};
  for (int dk = 0; dk < KCHUNK; dk += 32) {
    const float* Arow = &Aop[(size_t)(d0 + dk + lr) * lda + ca];
    const float* Brow = &Bop[(size_t)(d0 + dk + lr) * ldb + cb];
    float4 a0 = *(const float4*)&Arow[lc];
    float4 a1 = *(const float4*)&Arow[lc + 4];
    float4 b0 = *(const float4*)&Brow[lc];
    float4 b1 = *(const float4*)&Brow[lc + 4];
    __syncthreads();
    *(float4*)&Wa[lr][lc]     = a0;
    *(float4*)&Wa[lr][lc + 4] = a1;
    *(float4*)&Wb[lr][lc]     = b0;
    *(float4*)&Wb[lr][lc + 4] = b1;
    __syncthreads();
    #pragma unroll
    for (int k = 0; k < 32; k++) {
      float4 ra4 = *(const float4*)&Wa[k][ty * 4];
      float4 rb4 = *(const float4*)&Wb[k][tx * 4];
      float ra[4] = {ra4.x, ra4.y, ra4.z, ra4.w};
      float rb[4] = {rb4.x, rb4.y, rb4.z, rb4.w};
      #pragma unroll
      for (int i = 0; i < 4; i++)
        #pragma unroll
        for (int j = 0; j < 4; j++)
          acc[i][j] = fmaf(ra[i], rb[j], acc[i][j]);
    }
  }
  #pragma unroll
  for (int i = 0; i < 4; i++)
    #pragma unroll
    for (int j = 0; j < 4; j++)
      atomicAdd(&Out[(size_t)(ro + ty * 4 + i) * ldo + co + tx * 4 + j], acc[i][j]);
}

// ---- G = W^T W: four 128x128 quadrants, ksplit 64 (k-chunk 1024) -> 256 blocks
// (exactly 1/CU; r6 lesson: 192 blocks = idle CUs + 1 wave/SIMD stall city).
// Double-buffered LDS staging: next chunk's global loads issue before the FMA
// block so vmcnt drain overlaps compute. Staging writes are contiguous-row
// (conflict-free); frag reads are b128 broadcast / 2-way (free).
// Partials (4*64*16384 floats) -> scratch, no atomics.
__global__ __launch_bounds__(256) void k_G(const float* __restrict__ W,
    float* __restrict__ part) {
  const int tit[4] = {0, 0, 1, 1}, tjt[4] = {0, 1, 0, 1};
  int p = blockIdx.y;
  int c1 = tit[p] * 128, c2 = tjt[p] * 128;
  int d0 = blockIdx.x * 1024;
  __shared__ float Wa[2][32][132], Wb[2][32][132];
  int t = threadIdx.x;
  int tx = t & 15, ty = t >> 4;
  int half = (t >> 5) & 1, ql = t & 31, rowb = t >> 6;  // load map
  int cbase = (half ? c2 : c1) + ql * 4;
  float acc[2][2][4][4] = {};
  float4 v[8];
  #pragma unroll
  for (int rr = 0; rr < 8; rr++)
    v[rr] = *(const float4*)&W[(size_t)(d0 + rowb * 8 + rr) * C_ + cbase];
  #pragma unroll
  for (int rr = 0; rr < 8; rr++) {
    int row = rowb * 8 + rr;
    if (half == 0) *(float4*)&Wa[0][row][ql * 4] = v[rr];
    else           *(float4*)&Wb[0][row][ql * 4] = v[rr];
  }
  int cur = 0;
  for (int dk = 0; dk < 1024; dk += 32) {
    bool more = (dk + 32 < 1024);
    if (more) {
      #pragma unroll
      for (int rr = 0; rr < 8; rr++)
        v[rr] = *(const float4*)&W[(size_t)(d0 + dk + 32 + rowb * 8 + rr) * C_ + cbase];
    }
    __syncthreads();   // buf[cur] writes visible
    #pragma unroll 8
    for (int k = 0; k < 32; k++) {
      float4 ra0 = *(const float4*)&Wa[cur][k][ty * 4];
      float4 ra1 = *(const float4*)&Wa[cur][k][64 + ty * 4];
      float4 rb0 = *(const float4*)&Wb[cur][k][tx * 4];
      float4 rb1 = *(const float4*)&Wb[cur][k][64 + tx * 4];
      float A0[4] = {ra0.x, ra0.y, ra0.z, ra0.w};
      float A1[4] = {ra1.x, ra1.y, ra1.z, ra1.w};
      float B0[4] = {rb0.x, rb0.y, rb0.z, rb0.w};
      float B1[4] = {rb1.x, rb1.y, rb1.z, rb1.w};
      #pragma unroll
      for (int i = 0; i < 4; i++)
        #pragma unroll
        for (int j = 0; j < 4; j++) {
          acc[0][0][i][j] = fmaf(A0[i], B0[j], acc[0][0][i][j]);
          acc[0][1][i][j] = fmaf(A0[i], B1[j], acc[0][1][i][j]);
          acc[1][0][i][j] = fmaf(A1[i], B0[j], acc[1][0][i][j]);
          acc[1][1][i][j] = fmaf(A1[i], B1[j], acc[1][1][i][j]);
        }
    }
    if (more) {
      __syncthreads();   // all waves done reading buf[1-cur] (prev iter)
      #pragma unroll
      for (int rr = 0; rr < 8; rr++) {
        int row = rowb * 8 + rr;
        if (half == 0) *(float4*)&Wa[1 - cur][row][ql * 4] = v[rr];
        else           *(float4*)&Wb[1 - cur][row][ql * 4] = v[rr];
      }
      cur = 1 - cur;
    }
  }
  float* pp = &part[((size_t)p * 64 + blockIdx.x) * 16384];
  #pragma unroll
  for (int qi = 0; qi < 2; qi++)
    #pragma unroll
    for (int qj = 0; qj < 2; qj++)
      #pragma unroll
      for (int i = 0; i < 4; i++)
        *(float4*)&pp[(qi * 64 + ty * 4 + i) * 128 + qj * 64 + tx * 4] =
            *(float4*)&acc[qi][qj][i][0];
}

// ---- reduce 64 k-partials -> G (all 4 quadrants stored directly) ----
__global__ __launch_bounds__(256) void k_Gred(const float* __restrict__ part,
    float* __restrict__ G) {
  const int tit[4] = {0, 0, 1, 1}, tjt[4] = {0, 1, 0, 1};
  int p = blockIdx.y;
  int i = blockIdx.x * 256 + threadIdx.x;   // 0..16383
  const float* base = part + (size_t)p * 64 * 16384 + i;
  float s = 0.f;
  for (int kb = 0; kb < 64; kb++) s += base[(size_t)kb * 16384];
  int r = i >> 7, c = i & 127;
  G[(tit[p] * 128 + r) * C_ + tjt[p] * 128 + c] = s;
}

// ---- S = X^T X: full 16 tile pairs, ksplit 8x256 ----
__global__ __launch_bounds__(256) void k_S(const float* __restrict__ x, float* __restrict__ S) {
  int p = blockIdx.y;
  int ti = p >> 2, tj = p & 3;
  gemm_tt_tile<256>(x, C_, ti * 64, x, C_, tj * 64, blockIdx.x * 256,
                    S, C_, ti * 64, tj * 64);
}

// ---- A = resp^T X ----
__global__ __launch_bounds__(256) void k_A2(const float* __restrict__ resp,
    const float* __restrict__ x, float* __restrict__ A) {
  gemm_tt_tile<256>(resp, NE, 0, x, C_, blockIdx.y * 64, blockIdx.x * 256,
                    A, C_, 0, blockIdx.y * 64);
}

// ---- RR = resp^T resp ----
__global__ __launch_bounds__(256) void k_RR2(const float* __restrict__ resp,
    float* __restrict__ RR) {
  gemm_tt_tile<256>(resp, NE, 0, resp, NE, 0, blockIdx.x * 256, RR, NE, 0, 0);
}

// ---- sumresp ----
__global__ __launch_bounds__(256) void k_sr(const float* __restrict__ resp,
    float* __restrict__ sumresp) {
  int e = threadIdx.x & 63, part = threadIdx.x >> 6;
  int n0 = blockIdx.x * 256 + part * 64;
  float s = 0.f;
  for (int n = n0; n < n0 + 64; n++) s += resp[n * NE + e];
  __shared__ float red[256];
  red[threadIdx.x] = s;
  __syncthreads();
  if (part == 0)
    atomicAdd(&sumresp[e], red[e] + red[64 + e] + red[128 + e] + red[192 + e]);
}

// ---------------- Xsum ----------------
__global__ __launch_bounds__(256) void k_xsum(const float* __restrict__ x, float* __restrict__ xsum) {
  int n0 = blockIdx.x * 64;
  int c = threadIdx.x;
  float s = 0.f;
  for (int n = 0; n < 64; n++) s += x[(n0 + n) * C_ + c];
  atomicAdd(&xsum[c], s);
}

// ---- M = cen @ W (fp32). 64e x 64c tile, ksplit 128x512, partials ----
__global__ __launch_bounds__(256) void k_M(const float* __restrict__ cen,
    const float* __restrict__ W, float* __restrict__ mpart) {
  int kb = blockIdx.x;
  int c0 = blockIdx.y * 64;
  int d0 = kb * 512;
  __shared__ float As[32][68];
  __shared__ float Bs[32][68];
  int t = threadIdx.x;
  int tx = t & 15, ty = t >> 4;
  int e = t >> 2, dg = t & 3;
  int lr = t >> 3, lc = (t & 7) * 8;
  float acc[4][4] = {};
  for (int dk = 0; dk < 512; dk += 32) {
    const float* cr = &cen[(size_t)e * D_ + d0 + dk];
    float4 cv0 = *(const float4*)&cr[dg * 4];
    float4 cv1 = *(const float4*)&cr[16 + dg * 4];
    const float* wr = &W[(size_t)(d0 + dk + lr) * C_ + c0];
    float4 w0 = *(const float4*)&wr[lc];
    float4 w1 = *(const float4*)&wr[lc + 4];
    __syncthreads();
    As[dg * 4 + 0][e] = cv0.x; As[dg * 4 + 1][e] = cv0.y;
    As[dg * 4 + 2][e] = cv0.z; As[dg * 4 + 3][e] = cv0.w;
    As[16 + dg * 4 + 0][e] = cv1.x; As[16 + dg * 4 + 1][e] = cv1.y;
    As[16 + dg * 4 + 2][e] = cv1.z; As[16 + dg * 4 + 3][e] = cv1.w;
    *(float4*)&Bs[lr][lc]     = w0;
    *(float4*)&Bs[lr][lc + 4] = w1;
    __syncthreads();
    #pragma unroll 8
    for (int k = 0; k < 32; k++) {
      float4 ra4 = *(const float4*)&As[k][ty * 4];
      float4 rb4 = *(const float4*)&Bs[k][tx * 4];
      float ra[4] = {ra4.x, ra4.y, ra4.z, ra4.w};
      float rb[4] = {rb4.x, rb4.y, rb4.z, rb4.w};
      #pragma unroll
      for (int i = 0; i < 4; i++)
        #pragma unroll
        for (int j = 0; j < 4; j++)
          acc[i][j] = fmaf(ra[i], rb[j], acc[i][j]);
    }
  }
  float* pp = &mpart[(size_t)kb * 16384];
  #pragma unroll
  for (int i = 0; i < 4; i++)
    *(float4*)&pp[(ty * 4 + i) * C_ + c0 + tx * 4] = *(float4*)&acc[i][0];
}

// ---- reduce 128 k-partials -> M ----
__global__ __launch_bounds__(256) void k_Mred(const float* __restrict__ mpart,
    float* __restrict__ M) {
  int i = blockIdx.x * 256 + threadIdx.x;
  float s = 0.f;
  for (int kb = 0; kb < 128; kb++) s += mpart[(size_t)kb * 16384 + i];
  M[i] = s;
}

// ---------------- Wb[c] = sum_d b[d] W[d,c] (skip all-zero b chunks) ----------
__global__ __launch_bounds__(256) void k_Wb(const float* __restrict__ bmap,
    const float* __restrict__ W, float* __restrict__ Wb) {
  int d0 = blockIdx.x * 256;
  int c = threadIdx.x;
  __shared__ float bs[256];
  __shared__ int any;
  if (c == 0) any = 0;
  __syncthreads();
  float bv = bmap[d0 + c];
  bs[c] = bv;
  if (bv != 0.f) any = 1;
  __syncthreads();
  if (any == 0) return;
  float s = 0.f;
  for (int d = 0; d < 256; d++) s = fmaf(bs[d], W[(size_t)(d0 + d) * C_ + c], s);
  atomicAdd(&Wb[c], s);
}

// ---------------- y = X @ pw^T ----------------
__global__ __launch_bounds__(256) void k_y(const float* __restrict__ x,
    const float* __restrict__ pw, float* __restrict__ y) {
  int n0 = blockIdx.x * 64, k0 = blockIdx.y * 64;
  __shared__ float Xs[64][17], Ps[64][17];
  int t = threadIdx.x;
  int tx = t & 15, ty = t >> 4;
  int r = t >> 2, q4 = (t & 3) * 4;
  float acc[4][4] = {};
  for (int j0 = 0; j0 < 256; j0 += 16) {
    float4 va = *(const float4*)&x[(n0 + r) * C_ + j0 + q4];
    float4 vb = *(const float4*)&pw[(k0 + r) * C_ + j0 + q4];
    __syncthreads();
    Xs[r][q4] = va.x; Xs[r][q4+1] = va.y; Xs[r][q4+2] = va.z; Xs[r][q4+3] = va.w;
    Ps[r][q4] = vb.x; Ps[r][q4+1] = vb.y; Ps[r][q4+2] = vb.z; Ps[r][q4+3] = vb.w;
    __syncthreads();
    #pragma unroll
    for (int k = 0; k < 16; k++) {
      float ra[4], rb[4];
      #pragma unroll
      for (int i = 0; i < 4; i++) ra[i] = Xs[ty*4 + i][k];
      #pragma unroll
      for (int j = 0; j < 4; j++) rb[j] = Ps[tx*4 + j][k];
      #pragma unroll
      for (int i = 0; i < 4; i++)
        #pragma unroll
        for (int j = 0; j < 4; j++)
          acc[i][j] = fmaf(ra[i], rb[j], acc[i][j]);
    }
  }
  #pragma unroll
  for (int i = 0; i < 4; i++)
    #pragma unroll
    for (int j = 0; j < 4; j++)
      y[(n0 + ty*4 + i) * C_ + k0 + tx*4 + j] = acc[i][j];
}

// ------- resp softmax --------
__global__ __launch_bounds__(64) void k_resp(const float* __restrict__ x,
    const float* __restrict__ u, const float* __restrict__ M,
    const float* __restrict__ cn2, const float* __restrict__ cb,
    float* __restrict__ resp) {
  int n = blockIdx.x;
  int e = threadIdx.x;
  __shared__ float xs[256];
  *(float4*)&xs[e * 4] = *(const float4*)&x[n * C_ + e * 4];
  __syncthreads();
  const float* Me = M + e * C_;
  float s = 0.f;
  #pragma unroll 8
  for (int j = 0; j < 256; j += 4) {
    float4 m4 = *(const float4*)&Me[j];
    s = fmaf(xs[j],   m4.x, s);
    s = fmaf(xs[j+1], m4.y, s);
    s = fmaf(xs[j+2], m4.z, s);
    s = fmaf(xs[j+3], m4.w, s);
  }
  float uu = u[n * NE + e];
  float g = -logf(-logf(uu));
  float logit = 2.0f * (s + cb[e]) - cn2[e] + g;   // TAU == 1
  float m = logit;
  for (int off = 32; off > 0; off >>= 1) m = fmaxf(m, __shfl_xor(m, off));
  float ex = expf(logit - m);
  float sum = ex;
  for (int off = 32; off > 0; off >>= 1) sum += __shfl_xor(sum, off);
  resp[n * NE + e] = ex / sum;
}

// ------- routing (NO cap — r3 lesson) -------
__global__ __launch_bounds__(256) void k_route(const float* __restrict__ resp,
    unsigned int* __restrict__ cnt, int* __restrict__ tokidx,
    float* __restrict__ tokr, int* __restrict__ tslot) {
  int n = blockIdx.x * 256 + threadIdx.x;
  int s = 0;
  #pragma unroll 4
  for (int e = 0; e < NE; e++) {
    float r = resp[n * NE + e];
    if (r > RTHRESH) {
      unsigned pos = atomicAdd(&cnt[e], 1u);
      tokidx[e * 2048 + pos] = n;
      tokr[e * 2048 + pos] = r;
      s++;
    }
  }
  tslot[n] = s;
}

// ------- planner -------
__global__ void k_plan(const unsigned int* __restrict__ cnt,
    int* __restrict__ che, int* __restrict__ chb, int* __restrict__ nch) {
  if (threadIdx.x != 0 || blockIdx.x != 0) return;
  int ch = 0;
  for (int e = 0; e < NE; e++) {
    int c = (int)cnt[e];
    for (int b = 0; b < c && ch < CHMAX; b += 16) { che[ch] = e; chb[ch] = b; ch++; }
  }
  nch[0] = ch;
}

// ---------------- AG = A @ G, AWb ----------------
__global__ __launch_bounds__(256) void k_ag(const float* __restrict__ A,
    const float* __restrict__ G, const float* __restrict__ Wb,
    float* __restrict__ AG, float* __restrict__ AWb) {
  int e = blockIdx.x, c = threadIdx.x;
  float s = 0.f;
  for (int cp = 0; cp < C_; cp++) s = fmaf(A[e * C_ + cp], G[cp * C_ + c], s);
  AG[e * C_ + c] = s;
  float p = A[e * C_ + c] * Wb[c];
  __shared__ float red[256];
  red[c] = p;
  __syncthreads();
  for (int k = 128; k > 0; k >>= 1) {
    if (c < k) red[c] += red[c + k];
    __syncthreads();
  }
  if (c == 0) AWb[e] = red[0];
}

// ---------------- MA = M A^T, AGA = AG A^T ----------------
__global__ __launch_bounds__(256) void k_small64(const float* __restrict__ M,
    const float* __restrict__ A, const float* __restrict__ AG,
    float* __restrict__ MA, float* __restrict__ AGA) {
  int e = blockIdx.x;
  int f = threadIdx.x >> 2, q = threadIdx.x & 3;
  float s1 = 0.f, s2 = 0.f;
  for (int c = q * 64; c < q * 64 + 64; c++) {
    float a = A[f * C_ + c];
    s1 = fmaf(M[e * C_ + c], a, s1);
    s2 = fmaf(AG[e * C_ + c], a, s2);
  }
  __shared__ float r1[256], r2[256];
  r1[threadIdx.x] = s1; r2[threadIdx.x] = s2;
  __syncthreads();
  if (q == 0) {
    MA[e * NE + f]  = r1[f*4] + r1[f*4+1] + r1[f*4+2] + r1[f*4+3];
    AGA[e * NE + f] = r2[f*4] + r2[f*4+1] + r2[f*4+2] + r2[f*4+3];
  }
}

// ------- cnew[e,d] = decay*cen + alpha*(A_e.W_d + sr_e*b_d) -------
__global__ __launch_bounds__(256) void k_cnew(const float* __restrict__ A,
    const float* __restrict__ sumresp, const float* __restrict__ cen,
    const float* __restrict__ bmap, const float* __restrict__ W,
    float* __restrict__ cnew) {
  int d0 = blockIdx.x * 128;
  __shared__ float As[32][68];
  __shared__ float Bs[32][132];
  int t = threadIdx.x;
  int tx = t & 15, ty = t >> 4;
  int e = t >> 2, cg = t & 3;
  int dd = t >> 1, ch = (t & 1) * 16;
  float acc[4][2][4] = {};
  for (int c0 = 0; c0 < 256; c0 += 32) {
    const float* ar = &A[e * C_ + c0];
    float4 a0 = *(const float4*)&ar[cg * 4];
    float4 a1 = *(const float4*)&ar[16 + cg * 4];
    const float* wr = &W[(size_t)(d0 + dd) * C_ + c0 + ch];
    float4 w0 = *(const float4*)&wr[0];
    float4 w1 = *(const float4*)&wr[4];
    float4 w2 = *(const float4*)&wr[8];
    float4 w3 = *(const float4*)&wr[12];
    __syncthreads();
    As[cg * 4 + 0][e] = a0.x; As[cg * 4 + 1][e] = a0.y;
    As[cg * 4 + 2][e] = a0.z; As[cg * 4 + 3][e] = a0.w;
    As[16 + cg * 4 + 0][e] = a1.x; As[16 + cg * 4 + 1][e] = a1.y;
    As[16 + cg * 4 + 2][e] = a1.z; As[16 + cg * 4 + 3][e] = a1.w;
    Bs[ch + 0][dd] = w0.x;  Bs[ch + 1][dd] = w0.y;
    Bs[ch + 2][dd] = w0.z;  Bs[ch + 3][dd] = w0.w;
    Bs[ch + 4][dd] = w1.x;  Bs[ch + 5][dd] = w1.y;
    Bs[ch + 6][dd] = w1.z;  Bs[ch + 7][dd] = w1.w;
    Bs[ch + 8][dd] = w2.x;  Bs[ch + 9][dd] = w2.y;
    Bs[ch + 10][dd] = w2.z; Bs[ch + 11][dd] = w2.w;
    Bs[ch + 12][dd] = w3.x; Bs[ch + 13][dd] = w3.y;
    Bs[ch + 14][dd] = w3.z; Bs[ch + 15][dd] = w3.w;
    __syncthreads();
    #pragma unroll 8
    for (int k = 0; k < 32; k++) {
      float4 ra4 = *(const float4*)&As[k][ty * 4];
      float4 rb0 = *(const float4*)&Bs[k][tx * 4];
      float4 rb1 = *(const float4*)&Bs[k][64 + tx * 4];
      float ra[4] = {ra4.x, ra4.y, ra4.z, ra4.w};
      float b0[4] = {rb0.x, rb0.y, rb0.z, rb0.w};
      float b1[4] = {rb1.x, rb1.y, rb1.z, rb1.w};
      #pragma unroll
      for (int i = 0; i < 4; i++)
        #pragma unroll
        for (int j = 0; j < 4; j++) {
          acc[i][0][j] = fmaf(ra[i], b0[j], acc[i][0][j]);
          acc[i][1][j] = fmaf(ra[i], b1[j], acc[i][1][j]);
        }
    }
  }
  #pragma unroll
  for (int i = 0; i < 4; i++) {
    int ee = ty * 4 + i;
    float sr = sumresp[ee];
    #pragma unroll
    for (int q = 0; q < 2; q++) {
      int d = d0 + q * 64 + tx * 4;
      float4 cv = *(const float4*)&cen[(size_t)ee * D_ + d];
      float4 bv = *(const float4*)&bmap[d];
      float4 o;
      o.x = DECAYF * cv.x + ALPHA * (acc[i][q][0] + sr * bv.x);
      o.y = DECAYF * cv.y + ALPHA * (acc[i][q][1] + sr * bv.y);
      o.z = DECAYF * cv.z + ALPHA * (acc[i][q][2] + sr * bv.z);
      o.w = DECAYF * cv.w + ALPHA * (acc[i][q][3] + sr * bv.w);
      *(float4*)&cnew[(size_t)ee * D_ + d] = o;
    }
  }
}

// ---------------- CC0 = cen cen^T ----------------
__global__ __launch_bounds__(256) void k_CC(const float* __restrict__ cen, float* __restrict__ CC0) {
  int d0 = blockIdx.x * 512;
  __shared__ float cs[64][17];
  int t = threadIdx.x;
  int tx = t & 15, ty = t >> 4;
  int ea = t >> 2, k4 = (t & 3) * 4;
  float acc[4][4] = {};
  for (int dk = 0; dk < 512; dk += 16) {
    float4 v = *(const float4*)&cen[(size_t)ea * D_ + d0 + dk + k4];
    __syncthreads();
    cs[ea][k4] = v.x; cs[ea][k4+1] = v.y; cs[ea][k4+2] = v.z; cs[ea][k4+3] = v.w;
    __syncthreads();
    #pragma unroll
    for (int k = 0; k < 16; k++) {
      float a_[4], b_[4];
      #pragma unroll
      for (int i = 0; i < 4; i++) a_[i] = cs[ty*4 + i][k];
      #pragma unroll
      for (int j = 0; j < 4; j++) b_[j] = cs[tx*4 + j][k];
      #pragma unroll
      for (int i = 0; i < 4; i++)
        #pragma unroll
        for (int j = 0; j < 4; j++)
          acc[i][j] = fmaf(a_[i], b_[j], acc[i][j]);
    }
  }
  #pragma unroll
  for (int i = 0; i < 4; i++)
    #pragma unroll
    for (int j = 0; j < 4; j++)
      atomicAdd(&CC0[(ty*4 + i) * NE + tx*4 + j], acc[i][j]);
}

// ---------------- out init with bias ----------------
__global__ __launch_bounds__(256) void k_bias(const float* __restrict__ pwB, float* __restrict__ out) {
  int idx = blockIdx.x * 256 + threadIdx.x;
  out[idx] = pwB[idx & 255];
}

// ------- stage A: dense grouped GEMM -------
__global__ __launch_bounds__(256) void k_sA(const int* __restrict__ che,
    const int* __restrict__ chb, const int* __restrict__ nch,
    const unsigned int* __restrict__ cnt, const int* __restrict__ tokidx,
    const float* __restrict__ tokr, const int* __restrict__ tslot,
    const float* __restrict__ y, const float* __restrict__ cnew,
    float* __restrict__ out) {
  int nchv = nch[0];
  int i0 = blockIdx.y * 128;
  __shared__ int nsh[16]; __shared__ float rsh[16]; __shared__ int wsh[16];
  __shared__ float Ys[16][260];
  __shared__ float Bs[32][132];
  int t = threadIdx.x;
  for (int ch = blockIdx.x; ch < nchv; ch += SA_GRIDX) {
    int e = che[ch], base = chb[ch];
    int c = (int)cnt[e];
    __syncthreads();
    if (t < 16) {
      int idx = base + t;
      if (idx < c) {
        int n = tokidx[e * 2048 + idx];
        nsh[t] = n; rsh[t] = tokr[e * 2048 + idx]; wsh[t] = tslot[n];
      } else { nsh[t] = 0; rsh[t] = 0.f; wsh[t] = 2; }
    }
    __syncthreads();
    {
      int row = t >> 4, c0 = (t & 15) * 16;
      const float* yr = &y[nsh[row] * C_ + c0];
      float4 v0 = *(const float4*)&yr[0];
      float4 v1 = *(const float4*)&yr[4];
      float4 v2 = *(const float4*)&yr[8];
      float4 v3 = *(const float4*)&yr[12];
      *(float4*)&Ys[row][c0]      = v0;
      *(float4*)&Ys[row][c0 + 4]  = v1;
      *(float4*)&Ys[row][c0 + 8]  = v2;
      *(float4*)&Ys[row][c0 + 12] = v3;
    }
    int tx = t & 31, ty = t >> 5;
    int br = t >> 1, bk = (t & 1) * 16;
    float acc[2][4] = {};
    for (int k0 = 0; k0 < 256; k0 += 32) {
      const float* Brow = &cnew[(size_t)e * D_ + (size_t)(i0 + br) * C_ + k0 + bk];
      float4 b0 = *(const float4*)&Brow[0];
      float4 b1 = *(const float4*)&Brow[4];
      float4 b2 = *(const float4*)&Brow[8];
      float4 b3 = *(const float4*)&Brow[12];
      __syncthreads();
      Bs[bk+0][br]  = b0.x; Bs[bk+1][br]  = b0.y; Bs[bk+2][br]  = b0.z; Bs[bk+3][br]  = b0.w;
      Bs[bk+4][br]  = b1.x; Bs[bk+5][br]  = b1.y; Bs[bk+6][br]  = b1.z; Bs[bk+7][br]  = b1.w;
      Bs[bk+8][br]  = b2.x; Bs[bk+9][br]  = b2.y; Bs[bk+10][br] = b2.z; Bs[bk+11][br] = b2.w;
      Bs[bk+12][br] = b3.x; Bs[bk+13][br] = b3.y; Bs[bk+14][br] = b3.z; Bs[bk+15][br] = b3.w;
      __syncthreads();
      #pragma unroll
      for (int kk = 0; kk < 32; kk++) {
        float a0 = Ys[ty*2 + 0][k0 + kk];
        float a1 = Ys[ty*2 + 1][k0 + kk];
        float4 bv = *(const float4*)&Bs[kk][tx*4];
        acc[0][0] = fmaf(a0, bv.x, acc[0][0]); acc[0][1] = fmaf(a0, bv.y, acc[0][1]);
        acc[0][2] = fmaf(a0, bv.z, acc[0][2]); acc[0][3] = fmaf(a0, bv.w, acc[0][3]);
        acc[1][0] = fmaf(a1, bv.x, acc[1][0]); acc[1][1] = fmaf(a1, bv.y, acc[1][1]);
        acc[1][2] = fmaf(a1, bv.z, acc[1][2]); acc[1][3] = fmaf(a1, bv.w, acc[1][3]);
      }
    }
    #pragma unroll
    for (int i = 0; i < 2; i++) {
      int tk = ty*2 + i;
      float r = rsh[tk];
      if (r == 0.f) continue;
      int n = nsh[tk];
      float* op = &out[n * C_ + i0 + tx*4];
      if (wsh[tk] == 1) {
        float4 cur = *(const float4*)op;
        cur.x += r * acc[i][0]; cur.y += r * acc[i][1];
        cur.z += r * acc[i][2]; cur.w += r * acc[i][3];
        *(float4*)op = cur;
      } else {
        atomicAdd(op + 0, r * acc[i][0]);
        atomicAdd(op + 1, r * acc[i][1]);
        atomicAdd(op + 2, r * acc[i][2]);
        atomicAdd(op + 3, r * acc[i][3]);
      }
    }
  }
}

// ---- gsum = sum G .* S ----
__global__ __launch_bounds__(256) void k_gs(const float* __restrict__ G,
    const float* __restrict__ S, float* __restrict__ gsum) {
  int base = blockIdx.x * 1024 + threadIdx.x;
  float s = 0.f;
  #pragma unroll
  for (int q = 0; q < 4; q++) {
    int i = base + q * 256;
    s = fmaf(G[i], S[i], s);
  }
  __shared__ float red[256];
  red[threadIdx.x] = s;
  __syncthreads();
  for (int k = 128; k > 0; k >>= 1) {
    if (threadIdx.x < k) red[threadIdx.x] += red[threadIdx.x + k];
    __syncthreads();
  }
  if (threadIdx.x == 0) atomicAdd(gsum, red[0]);
}

// ---------------- loss assembly ----------------
__global__ __launch_bounds__(256) void k_finalize(
    const float* __restrict__ gsum, const float* __restrict__ M,
    const float* __restrict__ A, const float* __restrict__ AG,
    const float* __restrict__ CC0, const float* __restrict__ RR,
    const float* __restrict__ MA, const float* __restrict__ AGA,
    const float* __restrict__ Xsum, const float* __restrict__ Wb,
    const float* __restrict__ bb, const float* __restrict__ sr,
    const float* __restrict__ cb, const float* __restrict__ AWb,
    float* __restrict__ out) {
  int t = threadIdx.x;
  float a_gs = (t == 0) ? gsum[0] : 0.f;
  float a_am = 0.f, a_aag = 0.f;
  for (int i = t; i < 16384; i += 256) {
    float a = A[i];
    a_am  = fmaf(M[i], a, a_am);
    a_aag = fmaf(AG[i], a, a_aag);
  }
  float a_cc = 0.f, a_ma = 0.f, a_aga = 0.f, a_cbsr = 0.f, a_awbsr = 0.f, a_srsr = 0.f;
  for (int p = t; p < 4096; p += 256) {
    float r = RR[p];
    int e = p >> 6, f = p & 63;
    float srf = sr[f];
    a_cc    = fmaf(r, CC0[p], a_cc);
    a_ma    = fmaf(r, MA[p], a_ma);
    a_aga   = fmaf(r, AGA[p], a_aga);
    a_cbsr  = fmaf(r * cb[e], srf, a_cbsr);
    a_awbsr = fmaf(r * AWb[e], srf, a_awbsr);
    a_srsr  = fmaf(r * sr[e], srf, a_srsr);
  }
  float a_xw = Xsum[t] * Wb[t];
  float a_srcb = 0.f, a_srawb = 0.f, a_sr2 = 0.f;
  if (t < 64) { float s = sr[t]; a_srcb = s * cb[t]; a_srawb = s * AWb[t]; a_sr2 = s * s; }
  float v[13] = {a_gs, a_am, a_aag, a_cc, a_ma, a_aga, a_cbsr, a_awbsr, a_srsr,
                 a_xw, a_srcb, a_srawb, a_sr2};
  __shared__ float red[256];
  __shared__ float tot[13];
  for (int q = 0; q < 13; q++) {
    red[t] = v[q];
    __syncthreads();
    for (int s2 = 128; s2 > 0; s2 >>= 1) {
      if (t < s2) red[t] += red[t + s2];
      __syncthreads();
    }
    if (t == 0) tot[q] = red[0];
    __syncthreads();
  }
  if (t == 0) {
    const float q = DECAYF, al = ALPHA;
    float bbv = bb[0];
    float sumkeyf2 = tot[0] + 2.f * tot[9] + 2048.f * bbv;
    float cross = q * (tot[1] + tot[10]) + al * (tot[2] + 2.f * tot[11] + bbv * tot[12]);
    float sumq2 = q*q * tot[3] + 2.f*q*al * (tot[4] + tot[6])
                + al*al * (tot[5] + 2.f * tot[7] + bbv * tot[8]);
    out[524288] = (0.25f / (2048.0f * 65536.0f)) * (sumkeyf2 - 2.f * cross + sumq2);
  }
}

extern "C" void kernel_launch(void* const* d_in, const int* in_sizes, int n_in,
                              void* d_out, int out_size, void* d_ws, size_t ws_size,
                              hipStream_t stream) {
  const float* x    = (const float*)d_in[0];
  const float* u    = (const float*)d_in[1];
  const float* Wm   = (const float*)d_in[2];
  const float* bmap = (const float*)d_in[3];
  const float* pw   = (const float*)d_in[4];
  const float* pwB  = (const float*)d_in[5];
  const float* cen  = (const float*)d_in[6];
  float* out = (float*)d_out;
  float* ws  = (float*)d_ws;

  float* S_      = ws + OFF_S;
  float* Xsum    = ws + OFF_XSUM;
  float* G       = ws + OFF_G;
  float* M       = ws + OFF_M;
  float* Wb      = ws + OFF_WB;
  float* bb      = ws + OFF_BB;
  float* gsum    = ws + OFF_BB + 1;
  float* sumresp = ws + OFF_SUMR;
  float* A       = ws + OFF_A;
  float* CC0     = ws + OFF_CC0;
  float* RR      = ws + OFF_RR;
  unsigned int* cnt = (unsigned int*)(ws + OFF_CNT);
  float* cn2     = ws + OFF_CN2;
  float* cb      = ws + OFF_CB;
  int*   tslot   = (int*)(ws + OFF_TSLOT);
  float* resp    = ws + OFF_RESP;
  float* AG      = ws + OFF_AG;
  float* MA      = ws + OFF_MA;
  float* AGA     = ws + OFF_AGA;
  float* AWb     = ws + OFF_AWB;
  int*   che     = (int*)(ws + OFF_CHE);
  int*   chb     = (int*)(ws + OFF_CHB);
  int*   nch     = (int*)(ws + OFF_NCH);
  float* y       = ws + OFF_Y;
  float* cnew    = ws + OFF_CNEW;
  float* scratch = ws + OFF_CNEW;     // k_G / k_M partials (pre-cnew, sequential)
  int*   tokidx  = (int*)(ws + OFF_TIDX);
  float* tokr    = ws + OFF_TOKR;

  hipMemsetAsync(d_ws, 0, ZFLOATS * sizeof(float), stream);

  k_cstats<<<256, 256, 0, stream>>>(cen, bmap, cn2, cb);
  k_bb<<<4, 256, 0, stream>>>(bmap, bb);
  k_S<<<dim3(8, 16), 256, 0, stream>>>(x, S_);
  k_xsum<<<32, 256, 0, stream>>>(x, Xsum);
  k_G<<<dim3(64, 4), 256, 0, stream>>>(Wm, scratch);
  k_Gred<<<dim3(64, 4), 256, 0, stream>>>(scratch, G);
  k_M<<<dim3(128, 4), 256, 0, stream>>>(cen, Wm, scratch);
  k_Mred<<<64, 256, 0, stream>>>(scratch, M);
  k_CC<<<128, 256, 0, stream>>>(cen, CC0);
  k_Wb<<<256, 256, 0, stream>>>(bmap, Wm, Wb);
  k_y<<<dim3(32, 4), 256, 0, stream>>>(x, pw, y);
  k_resp<<<2048, 64, 0, stream>>>(x, u, M, cn2, cb, resp);
  k_route<<<8, 256, 0, stream>>>(resp, cnt, tokidx, tokr, tslot);
  k_A2<<<dim3(8, 4), 256, 0, stream>>>(resp, x, A);
  k_sr<<<8, 256, 0, stream>>>(resp, sumresp);
  k_RR2<<<8, 256, 0, stream>>>(resp, RR);
  k_plan<<<1, 64, 0, stream>>>(cnt, che, chb, nch);
  k_ag<<<64, 256, 0, stream>>>(A, G, Wb, AG, AWb);
  k_small64<<<64, 256, 0, stream>>>(M, A, AG, MA, AGA);
  k_cnew<<<512, 256, 0, stream>>>(A, sumresp, cen, bmap, Wm, cnew);
  k_bias<<<2048, 256, 0, stream>>>(pwB, out);
  k_sA<<<dim3(SA_GRIDX, 2), 256, 0, stream>>>(che, chb, nch, cnt, tokidx, tokr,
                                              tslot, y, cnew, out);
  k_gs<<<64, 256, 0, stream>>>(G, S_, gsum);
  k_finalize<<<1, 256, 0, stream>>>(gsum, M, A, AG, CC0, RR, MA, AGA, Xsum, Wb,
                                    bb, sumresp, cb, AWb, out);
}

// Round 8
// 514.155 us; speedup vs baseline: 1.2417x; 1.2417x over previous
//
#include <hip/hip_runtime.h>
#include <hip/hip_bf16.h>

// Problem dims
constexpr int N_TOK = 2048;   // T*B
constexpr int C_    = 256;    // in features (== R == OUT)
constexpr int NE    = 64;     // experts
constexpr int D_    = 65536;  // R*OUT centroid dim
constexpr float DECAYF = 0.999f;
constexpr float OMD    = 0.001f;
constexpr float ALPHA  = OMD / 2048.0f;   // (1-decay)/N
constexpr float RTHRESH = 1e-5f;
constexpr int CHMAX = 8448;
constexpr int SA_GRIDX = 512;

using bf16x8 = __attribute__((ext_vector_type(8))) short;
using f32x4  = __attribute__((ext_vector_type(4))) float;

// ---------- workspace layout (float offsets) ----------
constexpr size_t OFF_S     = 0;        // 65536  S = X^T X (full)
constexpr size_t OFF_XSUM  = 65536;    // 256
constexpr size_t OFF_G     = 65792;    // 65536  G = W^T W (full)
constexpr size_t OFF_M     = 131328;   // 16384  M = cen @ W
constexpr size_t OFF_WB    = 147712;   // 256    Wb = b^T W
constexpr size_t OFF_BB    = 147968;   // 16     bb[0] = ||b||^2
constexpr size_t OFF_SUMR  = 147984;   // 64     sum_n resp
constexpr size_t OFF_A     = 148048;   // 16384  A = resp^T X
constexpr size_t OFF_CC0   = 164432;   // 4096   cen cen^T
constexpr size_t OFF_RR    = 168528;   // 4096   resp^T resp
constexpr size_t OFF_CNT   = 172624;   // 64     per-expert token counts (uint)
constexpr size_t OFF_CN2   = 172688;   // 64
constexpr size_t OFF_CB    = 172752;   // 64
constexpr size_t OFF_TSLOT = 172816;   // 2048   per-token writer count (int)
constexpr size_t ZFLOATS   = 174864;
// overwritten-before-read zone:
constexpr size_t OFF_RESP  = 174864;   // 131072
constexpr size_t OFF_AG    = 174864;   // 16384 (overlay after resp dead)
constexpr size_t OFF_MA    = 191248;   // 4096
constexpr size_t OFF_AGA   = 195344;   // 4096
constexpr size_t OFF_AWB   = 199440;   // 64
constexpr size_t OFF_CHE   = 199504;   // 8448
constexpr size_t OFF_CHB   = 207952;   // 8448
constexpr size_t OFF_NCH   = 216400;   // 16
constexpr size_t OFF_Y     = 305936;   // 524288 y = X @ pw^T
constexpr size_t OFF_CNEW  = 830224;   // 4194304 ; ALSO reused (before k_cnew):
                                       //   k_G partials (10*64*4096 = 2.62M floats)
                                       //   then k_M partials (128*16384 = 2.10M)
constexpr size_t OFF_TIDX  = 5024528;  // 131072 (int)
constexpr size_t OFF_TOKR  = 5155600;  // 131072
// total 5286672 floats = 21,146,688 bytes

__device__ __forceinline__ unsigned pack_bf2(float a, float b) {
  __hip_bfloat16 ha = __float2bfloat16(a), hb = __float2bfloat16(b);
  unsigned short ua = *reinterpret_cast<unsigned short*>(&ha);
  unsigned short ub = *reinterpret_cast<unsigned short*>(&hb);
  return (unsigned)ua | ((unsigned)ub << 16);
}

// ------- centroid stats: cn2[e], cb[e] -------
__global__ __launch_bounds__(256) void k_cstats(const float* __restrict__ cen,
    const float* __restrict__ bmap, float* __restrict__ cn2, float* __restrict__ cb) {
  int e = blockIdx.x >> 2;
  int d0 = (blockIdx.x & 3) * 16384;
  const float* ce = cen + (size_t)e * D_ + d0;
  const float* bm = bmap + d0;
  float s2 = 0.f, sb = 0.f;
  for (int d = threadIdx.x; d < 16384; d += 256) {
    float v = ce[d];
    s2 = fmaf(v, v, s2);
    sb = fmaf(v, bm[d], sb);
  }
  __shared__ float r0[256], r1[256];
  r0[threadIdx.x] = s2; r1[threadIdx.x] = sb;
  __syncthreads();
  for (int s = 128; s > 0; s >>= 1) {
    if (threadIdx.x < s) { r0[threadIdx.x] += r0[threadIdx.x + s];
                           r1[threadIdx.x] += r1[threadIdx.x + s]; }
    __syncthreads();
  }
  if (threadIdx.x == 0) { atomicAdd(&cn2[e], r0[0]); atomicAdd(&cb[e], r1[0]); }
}

// ---------------- bb[0] = ||b||^2 ----------------
__global__ __launch_bounds__(256) void k_bb(const float* __restrict__ bmap, float* __restrict__ bb) {
  int base = blockIdx.x * 16384 + threadIdx.x;
  float s = 0.f;
  for (int q = 0; q < 64; q++) { float v = bmap[base + q * 256]; s = fmaf(v, v, s); }
  __shared__ float red[256];
  red[threadIdx.x] = s;
  __syncthreads();
  for (int k = 128; k > 0; k >>= 1) {
    if (threadIdx.x < k) red[threadIdx.x] += red[threadIdx.x + k];
    __syncthreads();
  }
  if (threadIdx.x == 0) atomicAdd(&bb[0], red[0]);
}

// ======== generic 64x64 gram-style tile (S / A2 / RR2) ========
template<int KCHUNK>
__device__ __forceinline__ void gemm_tt_tile(
    const float* __restrict__ Aop, int lda, int ca,
    const float* __restrict__ Bop, int ldb, int cb,
    int d0, float* __restrict__ Out, int ldo, int ro, int co) {
  __shared__ float Wa[32][68], Wb[32][68];
  int t = threadIdx.x;
  int tx = t & 15, ty = t >> 4;
  int lr = t >> 3, lc = (t & 7) * 8;
  float acc[4][4] = {};
  for (int dk = 0; dk < KCHUNK; dk += 32) {
    const float* Arow = &Aop[(size_t)(d0 + dk + lr) * lda + ca];
    const float* Brow = &Bop[(size_t)(d0 + dk + lr) * ldb + cb];
    float4 a0 = *(const float4*)&Arow[lc];
    float4 a1 = *(const float4*)&Arow[lc + 4];
    float4 b0 = *(const float4*)&Brow[lc];
    float4 b1 = *(const float4*)&Brow[lc + 4];
    __syncthreads();
    *(float4*)&Wa[lr][lc]     = a0;
    *(float4*)&Wa[lr][lc + 4] = a1;
    *(float4*)&Wb[lr][lc]     = b0;
    *(float4*)&Wb[lr][lc + 4] = b1;
    __syncthreads();
    #pragma unroll
    for (int k = 0; k < 32; k++) {
      float4 ra4 = *(const float4*)&Wa[k][ty * 4];
      float4 rb4 = *(const float4*)&Wb[k][tx * 4];
      float ra[4] = {ra4.x, ra4.y, ra4.z, ra4.w};
      float rb[4] = {rb4.x, rb4.y, rb4.z, rb4.w};
      #pragma unroll
      for (int i = 0; i < 4; i++)
        #pragma unroll
        for (int j = 0; j < 4; j++)
          acc[i][j] = fmaf(ra[i], rb[j], acc[i][j]);
    }
  }
  #pragma unroll
  for (int i = 0; i < 4; i++)
    #pragma unroll
    for (int j = 0; j < 4; j++)
      atomicAdd(&Out[(size_t)(ro + ty * 4 + i) * ldo + co + tx * 4 + j], acc[i][j]);
}

// ---- G = W^T W via bf16 MFMA (G feeds the LOSS only: bf16 rel err ~1e-3 ok).
// 64x64 tiles, 10 upper-tri pairs x ksplit 64 (k-chunk 1024) = 640 blocks.
// fp32 W -> bf16 fused into LDS staging (transposed: Wt[col][k], padded row=40).
// MFMA operands are wave-shared: ~26x less LDS traffic than the FMA core
// (r5-r7: 115/152/188 us, all pinned ~2.3x above the 82 us ds_read floor).
__global__ __launch_bounds__(256) void k_G(const float* __restrict__ W,
    float* __restrict__ part) {
  int p = blockIdx.y;
  int ti = 0, rem0 = p;
  while (rem0 >= 4 - ti) { rem0 -= 4 - ti; ti++; }
  int tj = ti + rem0;
  int c1 = ti * 64, c2 = tj * 64;
  int d0 = blockIdx.x * 1024;
  __shared__ unsigned short Wat[64][40], Wbt[64][40];  // [col][k], 80B row (16B-aligned)
  int t = threadIdx.x;
  int h = t >> 7;                 // 0: A-tile, 1: B-tile
  int rem = t & 127;
  int k2 = rem >> 3;              // 0..15 -> k pair base k2*2
  int c4b = rem & 7;
  int cbase = h ? c2 : c1;
  unsigned short (*dst)[40] = h ? Wbt : Wat;
  int l = t & 63, w = t >> 6;
  int m0 = w * 16;
  int lm = l & 15, q8 = (l >> 4) * 8;
  f32x4 acc[4] = {};
  for (int dk = 0; dk < 1024; dk += 32) {
    __syncthreads();   // protect previous chunk's frag reads
    #pragma unroll
    for (int it = 0; it < 2; it++) {
      int c4 = c4b + it * 8;
      const float* rp = &W[(size_t)(d0 + dk + k2 * 2) * C_ + cbase + c4 * 4];
      float4 g0 = *(const float4*)rp;
      float4 g1 = *(const float4*)(rp + C_);
      *(unsigned*)&dst[c4 * 4 + 0][k2 * 2] = pack_bf2(g0.x, g1.x);
      *(unsigned*)&dst[c4 * 4 + 1][k2 * 2] = pack_bf2(g0.y, g1.y);
      *(unsigned*)&dst[c4 * 4 + 2][k2 * 2] = pack_bf2(g0.z, g1.z);
      *(unsigned*)&dst[c4 * 4 + 3][k2 * 2] = pack_bf2(g0.w, g1.w);
    }
    __syncthreads();
    bf16x8 av = *(const bf16x8*)&Wat[m0 + lm][q8];
    #pragma unroll
    for (int j = 0; j < 4; j++) {
      bf16x8 bv = *(const bf16x8*)&Wbt[j * 16 + lm][q8];
      acc[j] = __builtin_amdgcn_mfma_f32_16x16x32_bf16(av, bv, acc[j], 0, 0, 0);
    }
  }
  // C/D layout: col = lane&15, row = (lane>>4)*4 + reg  [m89-verified]
  float* pp = &part[((size_t)p * 64 + blockIdx.x) * 4096];
  #pragma unroll
  for (int j = 0; j < 4; j++)
    #pragma unroll
    for (int r = 0; r < 4; r++)
      pp[(m0 + (l >> 4) * 4 + r) * 64 + j * 16 + lm] = acc[j][r];
}

// ---- reduce 64 k-partials -> G (mirror off-diagonal pairs) ----
__global__ __launch_bounds__(256) void k_Gred(const float* __restrict__ part,
    float* __restrict__ G) {
  int p = blockIdx.y;
  int ti = 0, rem0 = p;
  while (rem0 >= 4 - ti) { rem0 -= 4 - ti; ti++; }
  int tj = ti + rem0;
  int i = blockIdx.x * 256 + threadIdx.x;   // 0..4095
  const float* base = part + (size_t)p * 64 * 4096 + i;
  float s = 0.f;
  for (int kb = 0; kb < 64; kb++) s += base[(size_t)kb * 4096];
  int r = i >> 6, c = i & 63;
  G[(ti * 64 + r) * C_ + tj * 64 + c] = s;
  if (ti != tj) G[(tj * 64 + c) * C_ + ti * 64 + r] = s;
}

// ---- S = X^T X: full 16 tile pairs, ksplit 8x256 ----
__global__ __launch_bounds__(256) void k_S(const float* __restrict__ x, float* __restrict__ S) {
  int p = blockIdx.y;
  int ti = p >> 2, tj = p & 3;
  gemm_tt_tile<256>(x, C_, ti * 64, x, C_, tj * 64, blockIdx.x * 256,
                    S, C_, ti * 64, tj * 64);
}

// ---- A = resp^T X ----
__global__ __launch_bounds__(256) void k_A2(const float* __restrict__ resp,
    const float* __restrict__ x, float* __restrict__ A) {
  gemm_tt_tile<256>(resp, NE, 0, x, C_, blockIdx.y * 64, blockIdx.x * 256,
                    A, C_, 0, blockIdx.y * 64);
}

// ---- RR = resp^T resp ----
__global__ __launch_bounds__(256) void k_RR2(const float* __restrict__ resp,
    float* __restrict__ RR) {
  gemm_tt_tile<256>(resp, NE, 0, resp, NE, 0, blockIdx.x * 256, RR, NE, 0, 0);
}

// ---- sumresp ----
__global__ __launch_bounds__(256) void k_sr(const float* __restrict__ resp,
    float* __restrict__ sumresp) {
  int e = threadIdx.x & 63, part = threadIdx.x >> 6;
  int n0 = blockIdx.x * 256 + part * 64;
  float s = 0.f;
  for (int n = n0; n < n0 + 64; n++) s += resp[n * NE + e];
  __shared__ float red[256];
  red[threadIdx.x] = s;
  __syncthreads();
  if (part == 0)
    atomicAdd(&sumresp[e], red[e] + red[64 + e] + red[128 + e] + red[192 + e]);
}

// ---------------- Xsum ----------------
__global__ __launch_bounds__(256) void k_xsum(const float* __restrict__ x, float* __restrict__ xsum) {
  int n0 = blockIdx.x * 64;
  int c = threadIdx.x;
  float s = 0.f;
  for (int n = 0; n < 64; n++) s += x[(n0 + n) * C_ + c];
  atomicAdd(&xsum[c], s);
}

// ---- M = cen @ W (fp32, logits precision-critical). ksplit 128x512, partials ----
__global__ __launch_bounds__(256) void k_M(const float* __restrict__ cen,
    const float* __restrict__ W, float* __restrict__ mpart) {
  int kb = blockIdx.x;
  int c0 = blockIdx.y * 64;
  int d0 = kb * 512;
  __shared__ float As[32][68];
  __shared__ float Bs[32][68];
  int t = threadIdx.x;
  int tx = t & 15, ty = t >> 4;
  int e = t >> 2, dg = t & 3;
  int lr = t >> 3, lc = (t & 7) * 8;
  float acc[4][4] = {};
  for (int dk = 0; dk < 512; dk += 32) {
    const float* cr = &cen[(size_t)e * D_ + d0 + dk];
    float4 cv0 = *(const float4*)&cr[dg * 4];
    float4 cv1 = *(const float4*)&cr[16 + dg * 4];
    const float* wr = &W[(size_t)(d0 + dk + lr) * C_ + c0];
    float4 w0 = *(const float4*)&wr[lc];
    float4 w1 = *(const float4*)&wr[lc + 4];
    __syncthreads();
    As[dg * 4 + 0][e] = cv0.x; As[dg * 4 + 1][e] = cv0.y;
    As[dg * 4 + 2][e] = cv0.z; As[dg * 4 + 3][e] = cv0.w;
    As[16 + dg * 4 + 0][e] = cv1.x; As[16 + dg * 4 + 1][e] = cv1.y;
    As[16 + dg * 4 + 2][e] = cv1.z; As[16 + dg * 4 + 3][e] = cv1.w;
    *(float4*)&Bs[lr][lc]     = w0;
    *(float4*)&Bs[lr][lc + 4] = w1;
    __syncthreads();
    #pragma unroll 8
    for (int k = 0; k < 32; k++) {
      float4 ra4 = *(const float4*)&As[k][ty * 4];
      float4 rb4 = *(const float4*)&Bs[k][tx * 4];
      float ra[4] = {ra4.x, ra4.y, ra4.z, ra4.w};
      float rb[4] = {rb4.x, rb4.y, rb4.z, rb4.w};
      #pragma unroll
      for (int i = 0; i < 4; i++)
        #pragma unroll
        for (int j = 0; j < 4; j++)
          acc[i][j] = fmaf(ra[i], rb[j], acc[i][j]);
    }
  }
  float* pp = &mpart[(size_t)kb * 16384];
  #pragma unroll
  for (int i = 0; i < 4; i++)
    *(float4*)&pp[(ty * 4 + i) * C_ + c0 + tx * 4] = *(float4*)&acc[i][0];
}

// ---- reduce 128 k-partials -> M ----
__global__ __launch_bounds__(256) void k_Mred(const float* __restrict__ mpart,
    float* __restrict__ M) {
  int i = blockIdx.x * 256 + threadIdx.x;
  float s = 0.f;
  for (int kb = 0; kb < 128; kb++) s += mpart[(size_t)kb * 16384 + i];
  M[i] = s;
}

// ---------------- Wb[c] = sum_d b[d] W[d,c] (skip all-zero b chunks) ----------
__global__ __launch_bounds__(256) void k_Wb(const float* __restrict__ bmap,
    const float* __restrict__ W, float* __restrict__ Wb) {
  int d0 = blockIdx.x * 256;
  int c = threadIdx.x;
  __shared__ float bs[256];
  __shared__ int any;
  if (c == 0) any = 0;
  __syncthreads();
  float bv = bmap[d0 + c];
  bs[c] = bv;
  if (bv != 0.f) any = 1;
  __syncthreads();
  if (any == 0) return;
  float s = 0.f;
  for (int d = 0; d < 256; d++) s = fmaf(bs[d], W[(size_t)(d0 + d) * C_ + c], s);
  atomicAdd(&Wb[c], s);
}

// ---------------- y = X @ pw^T ----------------
__global__ __launch_bounds__(256) void k_y(const float* __restrict__ x,
    const float* __restrict__ pw, float* __restrict__ y) {
  int n0 = blockIdx.x * 64, k0 = blockIdx.y * 64;
  __shared__ float Xs[64][17], Ps[64][17];
  int t = threadIdx.x;
  int tx = t & 15, ty = t >> 4;
  int r = t >> 2, q4 = (t & 3) * 4;
  float acc[4][4] = {};
  for (int j0 = 0; j0 < 256; j0 += 16) {
    float4 va = *(const float4*)&x[(n0 + r) * C_ + j0 + q4];
    float4 vb = *(const float4*)&pw[(k0 + r) * C_ + j0 + q4];
    __syncthreads();
    Xs[r][q4] = va.x; Xs[r][q4+1] = va.y; Xs[r][q4+2] = va.z; Xs[r][q4+3] = va.w;
    Ps[r][q4] = vb.x; Ps[r][q4+1] = vb.y; Ps[r][q4+2] = vb.z; Ps[r][q4+3] = vb.w;
    __syncthreads();
    #pragma unroll
    for (int k = 0; k < 16; k++) {
      float ra[4], rb[4];
      #pragma unroll
      for (int i = 0; i < 4; i++) ra[i] = Xs[ty*4 + i][k];
      #pragma unroll
      for (int j = 0; j < 4; j++) rb[j] = Ps[tx*4 + j][k];
      #pragma unroll
      for (int i = 0; i < 4; i++)
        #pragma unroll
        for (int j = 0; j < 4; j++)
          acc[i][j] = fmaf(ra[i], rb[j], acc[i][j]);
    }
  }
  #pragma unroll
  for (int i = 0; i < 4; i++)
    #pragma unroll
    for (int j = 0; j < 4; j++)
      y[(n0 + ty*4 + i) * C_ + k0 + tx*4 + j] = acc[i][j];
}

// ------- resp softmax --------
__global__ __launch_bounds__(64) void k_resp(const float* __restrict__ x,
    const float* __restrict__ u, const float* __restrict__ M,
    const float* __restrict__ cn2, const float* __restrict__ cb,
    float* __restrict__ resp) {
  int n = blockIdx.x;
  int e = threadIdx.x;
  __shared__ float xs[256];
  *(float4*)&xs[e * 4] = *(const float4*)&x[n * C_ + e * 4];
  __syncthreads();
  const float* Me = M + e * C_;
  float s = 0.f;
  #pragma unroll 8
  for (int j = 0; j < 256; j += 4) {
    float4 m4 = *(const float4*)&Me[j];
    s = fmaf(xs[j],   m4.x, s);
    s = fmaf(xs[j+1], m4.y, s);
    s = fmaf(xs[j+2], m4.z, s);
    s = fmaf(xs[j+3], m4.w, s);
  }
  float uu = u[n * NE + e];
  float g = -logf(-logf(uu));
  float logit = 2.0f * (s + cb[e]) - cn2[e] + g;   // TAU == 1
  float m = logit;
  for (int off = 32; off > 0; off >>= 1) m = fmaxf(m, __shfl_xor(m, off));
  float ex = expf(logit - m);
  float sum = ex;
  for (int off = 32; off > 0; off >>= 1) sum += __shfl_xor(sum, off);
  resp[n * NE + e] = ex / sum;
}

// ------- routing (NO cap — r3 lesson) -------
__global__ __launch_bounds__(256) void k_route(const float* __restrict__ resp,
    unsigned int* __restrict__ cnt, int* __restrict__ tokidx,
    float* __restrict__ tokr, int* __restrict__ tslot) {
  int n = blockIdx.x * 256 + threadIdx.x;
  int s = 0;
  #pragma unroll 4
  for (int e = 0; e < NE; e++) {
    float r = resp[n * NE + e];
    if (r > RTHRESH) {
      unsigned pos = atomicAdd(&cnt[e], 1u);
      tokidx[e * 2048 + pos] = n;
      tokr[e * 2048 + pos] = r;
      s++;
    }
  }
  tslot[n] = s;
}

// ------- planner -------
__global__ void k_plan(const unsigned int* __restrict__ cnt,
    int* __restrict__ che, int* __restrict__ chb, int* __restrict__ nch) {
  if (threadIdx.x != 0 || blockIdx.x != 0) return;
  int ch = 0;
  for (int e = 0; e < NE; e++) {
    int c = (int)cnt[e];
    for (int b = 0; b < c && ch < CHMAX; b += 16) { che[ch] = e; chb[ch] = b; ch++; }
  }
  nch[0] = ch;
}

// ---------------- AG = A @ G, AWb ----------------
__global__ __launch_bounds__(256) void k_ag(const float* __restrict__ A,
    const float* __restrict__ G, const float* __restrict__ Wb,
    float* __restrict__ AG, float* __restrict__ AWb) {
  int e = blockIdx.x, c = threadIdx.x;
  float s = 0.f;
  for (int cp = 0; cp < C_; cp++) s = fmaf(A[e * C_ + cp], G[cp * C_ + c], s);
  AG[e * C_ + c] = s;
  float p = A[e * C_ + c] * Wb[c];
  __shared__ float red[256];
  red[c] = p;
  __syncthreads();
  for (int k = 128; k > 0; k >>= 1) {
    if (c < k) red[c] += red[c + k];
    __syncthreads();
  }
  if (c == 0) AWb[e] = red[0];
}

// ---------------- MA = M A^T, AGA = AG A^T ----------------
__global__ __launch_bounds__(256) void k_small64(const float* __restrict__ M,
    const float* __restrict__ A, const float* __restrict__ AG,
    float* __restrict__ MA, float* __restrict__ AGA) {
  int e = blockIdx.x;
  int f = threadIdx.x >> 2, q = threadIdx.x & 3;
  float s1 = 0.f, s2 = 0.f;
  for (int c = q * 64; c < q * 64 + 64; c++) {
    float a = A[f * C_ + c];
    s1 = fmaf(M[e * C_ + c], a, s1);
    s2 = fmaf(AG[e * C_ + c], a, s2);
  }
  __shared__ float r1[256], r2[256];
  r1[threadIdx.x] = s1; r2[threadIdx.x] = s2;
  __syncthreads();
  if (q == 0) {
    MA[e * NE + f]  = r1[f*4] + r1[f*4+1] + r1[f*4+2] + r1[f*4+3];
    AGA[e * NE + f] = r2[f*4] + r2[f*4+1] + r2[f*4+2] + r2[f*4+3];
  }
}

// ------- cnew[e,d] = decay*cen + alpha*(A_e.W_d + sr_e*b_d) -------
__global__ __launch_bounds__(256) void k_cnew(const float* __restrict__ A,
    const float* __restrict__ sumresp, const float* __restrict__ cen,
    const float* __restrict__ bmap, const float* __restrict__ W,
    float* __restrict__ cnew) {
  int d0 = blockIdx.x * 128;
  __shared__ float As[32][68];
  __shared__ float Bs[32][132];
  int t = threadIdx.x;
  int tx = t & 15, ty = t >> 4;
  int e = t >> 2, cg = t & 3;
  int dd = t >> 1, ch = (t & 1) * 16;
  float acc[4][2][4] = {};
  for (int c0 = 0; c0 < 256; c0 += 32) {
    const float* ar = &A[e * C_ + c0];
    float4 a0 = *(const float4*)&ar[cg * 4];
    float4 a1 = *(const float4*)&ar[16 + cg * 4];
    const float* wr = &W[(size_t)(d0 + dd) * C_ + c0 + ch];
    float4 w0 = *(const float4*)&wr[0];
    float4 w1 = *(const float4*)&wr[4];
    float4 w2 = *(const float4*)&wr[8];
    float4 w3 = *(const float4*)&wr[12];
    __syncthreads();
    As[cg * 4 + 0][e] = a0.x; As[cg * 4 + 1][e] = a0.y;
    As[cg * 4 + 2][e] = a0.z; As[cg * 4 + 3][e] = a0.w;
    As[16 + cg * 4 + 0][e] = a1.x; As[16 + cg * 4 + 1][e] = a1.y;
    As[16 + cg * 4 + 2][e] = a1.z; As[16 + cg * 4 + 3][e] = a1.w;
    Bs[ch + 0][dd] = w0.x;  Bs[ch + 1][dd] = w0.y;
    Bs[ch + 2][dd] = w0.z;  Bs[ch + 3][dd] = w0.w;
    Bs[ch + 4][dd] = w1.x;  Bs[ch + 5][dd] = w1.y;
    Bs[ch + 6][dd] = w1.z;  Bs[ch + 7][dd] = w1.w;
    Bs[ch + 8][dd] = w2.x;  Bs[ch + 9][dd] = w2.y;
    Bs[ch + 10][dd] = w2.z; Bs[ch + 11][dd] = w2.w;
    Bs[ch + 12][dd] = w3.x; Bs[ch + 13][dd] = w3.y;
    Bs[ch + 14][dd] = w3.z; Bs[ch + 15][dd] = w3.w;
    __syncthreads();
    #pragma unroll 8
    for (int k = 0; k < 32; k++) {
      float4 ra4 = *(const float4*)&As[k][ty * 4];
      float4 rb0 = *(const float4*)&Bs[k][tx * 4];
      float4 rb1 = *(const float4*)&Bs[k][64 + tx * 4];
      float ra[4] = {ra4.x, ra4.y, ra4.z, ra4.w};
      float b0[4] = {rb0.x, rb0.y, rb0.z, rb0.w};
      float b1[4] = {rb1.x, rb1.y, rb1.z, rb1.w};
      #pragma unroll
      for (int i = 0; i < 4; i++)
        #pragma unroll
        for (int j = 0; j < 4; j++) {
          acc[i][0][j] = fmaf(ra[i], b0[j], acc[i][0][j]);
          acc[i][1][j] = fmaf(ra[i], b1[j], acc[i][1][j]);
        }
    }
  }
  #pragma unroll
  for (int i = 0; i < 4; i++) {
    int ee = ty * 4 + i;
    float sr = sumresp[ee];
    #pragma unroll
    for (int q = 0; q < 2; q++) {
      int d = d0 + q * 64 + tx * 4;
      float4 cv = *(const float4*)&cen[(size_t)ee * D_ + d];
      float4 bv = *(const float4*)&bmap[d];
      float4 o;
      o.x = DECAYF * cv.x + ALPHA * (acc[i][q][0] + sr * bv.x);
      o.y = DECAYF * cv.y + ALPHA * (acc[i][q][1] + sr * bv.y);
      o.z = DECAYF * cv.z + ALPHA * (acc[i][q][2] + sr * bv.z);
      o.w = DECAYF * cv.w + ALPHA * (acc[i][q][3] + sr * bv.w);
      *(float4*)&cnew[(size_t)ee * D_ + d] = o;
    }
  }
}

// ---------------- CC0 = cen cen^T ----------------
__global__ __launch_bounds__(256) void k_CC(const float* __restrict__ cen, float* __restrict__ CC0) {
  int d0 = blockIdx.x * 512;
  __shared__ float cs[64][17];
  int t = threadIdx.x;
  int tx = t & 15, ty = t >> 4;
  int ea = t >> 2, k4 = (t & 3) * 4;
  float acc[4][4] = {};
  for (int dk = 0; dk < 512; dk += 16) {
    float4 v = *(const float4*)&cen[(size_t)ea * D_ + d0 + dk + k4];
    __syncthreads();
    cs[ea][k4] = v.x; cs[ea][k4+1] = v.y; cs[ea][k4+2] = v.z; cs[ea][k4+3] = v.w;
    __syncthreads();
    #pragma unroll
    for (int k = 0; k < 16; k++) {
      float a_[4], b_[4];
      #pragma unroll
      for (int i = 0; i < 4; i++) a_[i] = cs[ty*4 + i][k];
      #pragma unroll
      for (int j = 0; j < 4; j++) b_[j] = cs[tx*4 + j][k];
      #pragma unroll
      for (int i = 0; i < 4; i++)
        #pragma unroll
        for (int j = 0; j < 4; j++)
          acc[i][j] = fmaf(a_[i], b_[j], acc[i][j]);
    }
  }
  #pragma unroll
  for (int i = 0; i < 4; i++)
    #pragma unroll
    for (int j = 0; j < 4; j++)
      atomicAdd(&CC0[(ty*4 + i) * NE + tx*4 + j], acc[i][j]);
}

// ---------------- out init with bias ----------------
__global__ __launch_bounds__(256) void k_bias(const float* __restrict__ pwB, float* __restrict__ out) {
  int idx = blockIdx.x * 256 + threadIdx.x;
  out[idx] = pwB[idx & 255];
}

// ------- stage A: dense grouped GEMM -------
__global__ __launch_bounds__(256) void k_sA(const int* __restrict__ che,
    const int* __restrict__ chb, const int* __restrict__ nch,
    const unsigned int* __restrict__ cnt, const int* __restrict__ tokidx,
    const float* __restrict__ tokr, const int* __restrict__ tslot,
    const float* __restrict__ y, const float* __restrict__ cnew,
    float* __restrict__ out) {
  int nchv = nch[0];
  int i0 = blockIdx.y * 128;
  __shared__ int nsh[16]; __shared__ float rsh[16]; __shared__ int wsh[16];
  __shared__ float Ys[16][260];
  __shared__ float Bs[32][132];
  int t = threadIdx.x;
  for (int ch = blockIdx.x; ch < nchv; ch += SA_GRIDX) {
    int e = che[ch], base = chb[ch];
    int c = (int)cnt[e];
    __syncthreads();
    if (t < 16) {
      int idx = base + t;
      if (idx < c) {
        int n = tokidx[e * 2048 + idx];
        nsh[t] = n; rsh[t] = tokr[e * 2048 + idx]; wsh[t] = tslot[n];
      } else { nsh[t] = 0; rsh[t] = 0.f; wsh[t] = 2; }
    }
    __syncthreads();
    {
      int row = t >> 4, c0 = (t & 15) * 16;
      const float* yr = &y[nsh[row] * C_ + c0];
      float4 v0 = *(const float4*)&yr[0];
      float4 v1 = *(const float4*)&yr[4];
      float4 v2 = *(const float4*)&yr[8];
      float4 v3 = *(const float4*)&yr[12];
      *(float4*)&Ys[row][c0]      = v0;
      *(float4*)&Ys[row][c0 + 4]  = v1;
      *(float4*)&Ys[row][c0 + 8]  = v2;
      *(float4*)&Ys[row][c0 + 12] = v3;
    }
    int tx = t & 31, ty = t >> 5;
    int br = t >> 1, bk = (t & 1) * 16;
    float acc[2][4] = {};
    for (int k0 = 0; k0 < 256; k0 += 32) {
      const float* Brow = &cnew[(size_t)e * D_ + (size_t)(i0 + br) * C_ + k0 + bk];
      float4 b0 = *(const float4*)&Brow[0];
      float4 b1 = *(const float4*)&Brow[4];
      float4 b2 = *(const float4*)&Brow[8];
      float4 b3 = *(const float4*)&Brow[12];
      __syncthreads();
      Bs[bk+0][br]  = b0.x; Bs[bk+1][br]  = b0.y; Bs[bk+2][br]  = b0.z; Bs[bk+3][br]  = b0.w;
      Bs[bk+4][br]  = b1.x; Bs[bk+5][br]  = b1.y; Bs[bk+6][br]  = b1.z; Bs[bk+7][br]  = b1.w;
      Bs[bk+8][br]  = b2.x; Bs[bk+9][br]  = b2.y; Bs[bk+10][br] = b2.z; Bs[bk+11][br] = b2.w;
      Bs[bk+12][br] = b3.x; Bs[bk+13][br] = b3.y; Bs[bk+14][br] = b3.z; Bs[bk+15][br] = b3.w;
      __syncthreads();
      #pragma unroll
      for (int kk = 0; kk < 32; kk++) {
        float a0 = Ys[ty*2 + 0][k0 + kk];
        float a1 = Ys[ty*2 + 1][k0 + kk];
        float4 bv = *(const float4*)&Bs[kk][tx*4];
        acc[0][0] = fmaf(a0, bv.x, acc[0][0]); acc[0][1] = fmaf(a0, bv.y, acc[0][1]);
        acc[0][2] = fmaf(a0, bv.z, acc[0][2]); acc[0][3] = fmaf(a0, bv.w, acc[0][3]);
        acc[1][0] = fmaf(a1, bv.x, acc[1][0]); acc[1][1] = fmaf(a1, bv.y, acc[1][1]);
        acc[1][2] = fmaf(a1, bv.z, acc[1][2]); acc[1][3] = fmaf(a1, bv.w, acc[1][3]);
      }
    }
    #pragma unroll
    for (int i = 0; i < 2; i++) {
      int tk = ty*2 + i;
      float r = rsh[tk];
      if (r == 0.f) continue;
      int n = nsh[tk];
      float* op = &out[n * C_ + i0 + tx*4];
      if (wsh[tk] == 1) {
        float4 cur = *(const float4*)op;
        cur.x += r * acc[i][0]; cur.y += r * acc[i][1];
        cur.z += r * acc[i][2]; cur.w += r * acc[i][3];
        *(float4*)op = cur;
      } else {
        atomicAdd(op + 0, r * acc[i][0]);
        atomicAdd(op + 1, r * acc[i][1]);
        atomicAdd(op + 2, r * acc[i][2]);
        atomicAdd(op + 3, r * acc[i][3]);
      }
    }
  }
}

// ---- gsum = sum G .* S ----
__global__ __launch_bounds__(256) void k_gs(const float* __restrict__ G,
    const float* __restrict__ S, float* __restrict__ gsum) {
  int base = blockIdx.x * 1024 + threadIdx.x;
  float s = 0.f;
  #pragma unroll
  for (int q = 0; q < 4; q++) {
    int i = base + q * 256;
    s = fmaf(G[i], S[i], s);
  }
  __shared__ float red[256];
  red[threadIdx.x] = s;
  __syncthreads();
  for (int k = 128; k > 0; k >>= 1) {
    if (threadIdx.x < k) red[threadIdx.x] += red[threadIdx.x + k];
    __syncthreads();
  }
  if (threadIdx.x == 0) atomicAdd(gsum, red[0]);
}

// ---------------- loss assembly ----------------
__global__ __launch_bounds__(256) void k_finalize(
    const float* __restrict__ gsum, const float* __restrict__ M,
    const float* __restrict__ A, const float* __restrict__ AG,
    const float* __restrict__ CC0, const float* __restrict__ RR,
    const float* __restrict__ MA, const float* __restrict__ AGA,
    const float* __restrict__ Xsum, const float* __restrict__ Wb,
    const float* __restrict__ bb, const float* __restrict__ sr,
    const float* __restrict__ cb, const float* __restrict__ AWb,
    float* __restrict__ out) {
  int t = threadIdx.x;
  float a_gs = (t == 0) ? gsum[0] : 0.f;
  float a_am = 0.f, a_aag = 0.f;
  for (int i = t; i < 16384; i += 256) {
    float a = A[i];
    a_am  = fmaf(M[i], a, a_am);
    a_aag = fmaf(AG[i], a, a_aag);
  }
  float a_cc = 0.f, a_ma = 0.f, a_aga = 0.f, a_cbsr = 0.f, a_awbsr = 0.f, a_srsr = 0.f;
  for (int p = t; p < 4096; p += 256) {
    float r = RR[p];
    int e = p >> 6, f = p & 63;
    float srf = sr[f];
    a_cc    = fmaf(r, CC0[p], a_cc);
    a_ma    = fmaf(r, MA[p], a_ma);
    a_aga   = fmaf(r, AGA[p], a_aga);
    a_cbsr  = fmaf(r * cb[e], srf, a_cbsr);
    a_awbsr = fmaf(r * AWb[e], srf, a_awbsr);
    a_srsr  = fmaf(r * sr[e], srf, a_srsr);
  }
  float a_xw = Xsum[t] * Wb[t];
  float a_srcb = 0.f, a_srawb = 0.f, a_sr2 = 0.f;
  if (t < 64) { float s = sr[t]; a_srcb = s * cb[t]; a_srawb = s * AWb[t]; a_sr2 = s * s; }
  float v[13] = {a_gs, a_am, a_aag, a_cc, a_ma, a_aga, a_cbsr, a_awbsr, a_srsr,
                 a_xw, a_srcb, a_srawb, a_sr2};
  __shared__ float red[256];
  __shared__ float tot[13];
  for (int q = 0; q < 13; q++) {
    red[t] = v[q];
    __syncthreads();
    for (int s2 = 128; s2 > 0; s2 >>= 1) {
      if (t < s2) red[t] += red[t + s2];
      __syncthreads();
    }
    if (t == 0) tot[q] = red[0];
    __syncthreads();
  }
  if (t == 0) {
    const float q = DECAYF, al = ALPHA;
    float bbv = bb[0];
    float sumkeyf2 = tot[0] + 2.f * tot[9] + 2048.f * bbv;
    float cross = q * (tot[1] + tot[10]) + al * (tot[2] + 2.f * tot[11] + bbv * tot[12]);
    float sumq2 = q*q * tot[3] + 2.f*q*al * (tot[4] + tot[6])
                + al*al * (tot[5] + 2.f * tot[7] + bbv * tot[8]);
    out[524288] = (0.25f / (2048.0f * 65536.0f)) * (sumkeyf2 - 2.f * cross + sumq2);
  }
}

extern "C" void kernel_launch(void* const* d_in, const int* in_sizes, int n_in,
                              void* d_out, int out_size, void* d_ws, size_t ws_size,
                              hipStream_t stream) {
  const float* x    = (const float*)d_in[0];
  const float* u    = (const float*)d_in[1];
  const float* Wm   = (const float*)d_in[2];
  const float* bmap = (const float*)d_in[3];
  const float* pw   = (const float*)d_in[4];
  const float* pwB  = (const float*)d_in[5];
  const float* cen  = (const float*)d_in[6];
  float* out = (float*)d_out;
  float* ws  = (float*)d_ws;

  float* S_      = ws + OFF_S;
  float* Xsum    = ws + OFF_XSUM;
  float* G       = ws + OFF_G;
  float* M       = ws + OFF_M;
  float* Wb      = ws + OFF_WB;
  float* bb      = ws + OFF_BB;
  float* gsum    = ws + OFF_BB + 1;
  float* sumresp = ws + OFF_SUMR;
  float* A       = ws + OFF_A;
  float* CC0     = ws + OFF_CC0;
  float* RR      = ws + OFF_RR;
  unsigned int* cnt = (unsigned int*)(ws + OFF_CNT);
  float* cn2     = ws + OFF_CN2;
  float* cb      = ws + OFF_CB;
  int*   tslot   = (int*)(ws + OFF_TSLOT);
  float* resp    = ws + OFF_RESP;
  float* AG      = ws + OFF_AG;
  float* MA      = ws + OFF_MA;
  float* AGA     = ws + OFF_AGA;
  float* AWb     = ws + OFF_AWB;
  int*   che     = (int*)(ws + OFF_CHE);
  int*   chb     = (int*)(ws + OFF_CHB);
  int*   nch     = (int*)(ws + OFF_NCH);
  float* y       = ws + OFF_Y;
  float* cnew    = ws + OFF_CNEW;
  float* scratch = ws + OFF_CNEW;     // k_G / k_M partials (pre-cnew, sequential)
  int*   tokidx  = (int*)(ws + OFF_TIDX);
  float* tokr    = ws + OFF_TOKR;

  hipMemsetAsync(d_ws, 0, ZFLOATS * sizeof(float), stream);

  k_cstats<<<256, 256, 0, stream>>>(cen, bmap, cn2, cb);
  k_bb<<<4, 256, 0, stream>>>(bmap, bb);
  k_S<<<dim3(8, 16), 256, 0, stream>>>(x, S_);
  k_xsum<<<32, 256, 0, stream>>>(x, Xsum);
  k_G<<<dim3(64, 10), 256, 0, stream>>>(Wm, scratch);
  k_Gred<<<dim3(16, 10), 256, 0, stream>>>(scratch, G);
  k_M<<<dim3(128, 4), 256, 0, stream>>>(cen, Wm, scratch + 2621440);
  k_Mred<<<64, 256, 0, stream>>>(scratch + 2621440, M);
  k_CC<<<128, 256, 0, stream>>>(cen, CC0);
  k_Wb<<<256, 256, 0, stream>>>(bmap, Wm, Wb);
  k_y<<<dim3(32, 4), 256, 0, stream>>>(x, pw, y);
  k_resp<<<2048, 64, 0, stream>>>(x, u, M, cn2, cb, resp);
  k_route<<<8, 256, 0, stream>>>(resp, cnt, tokidx, tokr, tslot);
  k_A2<<<dim3(8, 4), 256, 0, stream>>>(resp, x, A);
  k_sr<<<8, 256, 0, stream>>>(resp, sumresp);
  k_RR2<<<8, 256, 0, stream>>>(resp, RR);
  k_plan<<<1, 64, 0, stream>>>(cnt, che, chb, nch);
  k_ag<<<64, 256, 0, stream>>>(A, G, Wb, AG, AWb);
  k_small64<<<64, 256, 0, stream>>>(M, A, AG, MA, AGA);
  k_cnew<<<512, 256, 0, stream>>>(A, sumresp, cen, bmap, Wm, cnew);
  k_bias<<<2048, 256, 0, stream>>>(pwB, out);
  k_sA<<<dim3(SA_GRIDX, 2), 256, 0, stream>>>(che, chb, nch, cnt, tokidx, tokr,
                                              tslot, y, cnew, out);
  k_gs<<<64, 256, 0, stream>>>(G, S_, gsum);
  k_finalize<<<1, 256, 0, stream>>>(gsum, M, A, AG, CC0, RR, MA, AGA, Xsum, Wb,
                                    bb, sumresp, cb, AWb, out);
}